// Round 4
// baseline (399.472 us; speedup 1.0000x reference)
//
#include <hip/hip_runtime.h>
#include <hip/hip_bf16.h>
#include <stdint.h>

#define DIM   1024
#define ODIM  3072
#define MROWS 32768   // B(8) * N(4096)
#define RANK  8

typedef unsigned short u16;
typedef __attribute__((ext_vector_type(8))) short short8;
typedef __attribute__((ext_vector_type(8))) unsigned short u16x8;
typedef __attribute__((ext_vector_type(4))) float f32x4;

__device__ __forceinline__ u16 f2bf(float f) {
    uint32_t u = __float_as_uint(f);
    u += 0x7fffu + ((u >> 16) & 1u);   // RNE
    return (u16)(u >> 16);
}
__device__ __forceinline__ float bf2f(u16 h) {
    return __uint_as_float(((uint32_t)h) << 16);
}

__device__ __forceinline__ void gl2lds16(const void* g, void* l) {
    __builtin_amdgcn_global_load_lds(
        (const __attribute__((address_space(1))) void*)(uintptr_t)g,
        (__attribute__((address_space(3))) void*)(uint32_t)(uintptr_t)l,
        16, 0, 0);
}

#define BAR()   do { asm volatile("" ::: "memory"); __builtin_amdgcn_s_barrier(); asm volatile("" ::: "memory"); } while (0)
#define WAITV4() asm volatile("s_waitcnt vmcnt(4)" ::: "memory")
#define WAITV2() asm volatile("s_waitcnt vmcnt(2)" ::: "memory")
#define WAITV0() asm volatile("s_waitcnt vmcnt(0)" ::: "memory")
#define SCHED0() __builtin_amdgcn_sched_barrier(0)

// ---------------- f32 -> bf16 conversion ----------------
__global__ __launch_bounds__(256) void k_convert(const float* __restrict__ src,
                                                 u16* __restrict__ dst, int n) {
    const int stride = gridDim.x * blockDim.x;
    for (int t = blockIdx.x * blockDim.x + threadIdx.x; t * 8 < n; t += stride) {
        const int i = t * 8;
        float4 a = *reinterpret_cast<const float4*>(src + i);
        float4 b = *reinterpret_cast<const float4*>(src + i + 4);
        u16x8 o;
        o[0] = f2bf(a.x); o[1] = f2bf(a.y); o[2] = f2bf(a.z); o[3] = f2bf(a.w);
        o[4] = f2bf(b.x); o[5] = f2bf(b.y); o[6] = f2bf(b.z); o[7] = f2bf(b.w);
        *reinterpret_cast<u16x8*>(dst + i) = o;
    }
}

// ---------------- xa = x @ A[idx]  (32768 x 8, q and v) ----------------
__global__ __launch_bounds__(256) void k_lora_xa(const u16* __restrict__ Xc,
                                                 const float* __restrict__ Aq_pool,
                                                 const float* __restrict__ Av_pool,
                                                 const int* __restrict__ idx,
                                                 float* __restrict__ xaq,
                                                 float* __restrict__ xav) {
    __shared__ float sA[2][DIM * RANK];
    const int rowBase = blockIdx.x * 32;
    const int p = idx[rowBase >> 12];
    const float* gAq = Aq_pool + (size_t)p * (DIM * RANK);
    const float* gAv = Av_pool + (size_t)p * (DIM * RANK);
    for (int t = threadIdx.x; t < DIM * RANK / 4; t += 256) {
        reinterpret_cast<float4*>(sA[0])[t] = reinterpret_cast<const float4*>(gAq)[t];
        reinterpret_cast<float4*>(sA[1])[t] = reinterpret_cast<const float4*>(gAv)[t];
    }
    __syncthreads();
    const int wave = threadIdx.x >> 6, lane = threadIdx.x & 63;
    for (int rr = 0; rr < 8; ++rr) {
        const int row = rowBase + wave * 8 + rr;
        const u16* xr = Xc + (size_t)row * DIM;
        float aq[8] = {0,0,0,0,0,0,0,0};
        float av[8] = {0,0,0,0,0,0,0,0};
        #pragma unroll
        for (int ii = 0; ii < 16; ++ii) {
            const int i = ii * 64 + lane;
            const float xv = bf2f(xr[i]);
            float4 qa = reinterpret_cast<const float4*>(&sA[0][i * 8])[0];
            float4 qb = reinterpret_cast<const float4*>(&sA[0][i * 8])[1];
            float4 va = reinterpret_cast<const float4*>(&sA[1][i * 8])[0];
            float4 vb = reinterpret_cast<const float4*>(&sA[1][i * 8])[1];
            aq[0] += xv * qa.x; aq[1] += xv * qa.y; aq[2] += xv * qa.z; aq[3] += xv * qa.w;
            aq[4] += xv * qb.x; aq[5] += xv * qb.y; aq[6] += xv * qb.z; aq[7] += xv * qb.w;
            av[0] += xv * va.x; av[1] += xv * va.y; av[2] += xv * va.z; av[3] += xv * va.w;
            av[4] += xv * vb.x; av[5] += xv * vb.y; av[6] += xv * vb.z; av[7] += xv * vb.w;
        }
        #pragma unroll
        for (int off = 32; off > 0; off >>= 1) {
            #pragma unroll
            for (int r = 0; r < 8; ++r) {
                aq[r] += __shfl_xor(aq[r], off);
                av[r] += __shfl_xor(av[r], off);
            }
        }
        if (lane == 0) {
            #pragma unroll
            for (int r = 0; r < 8; ++r) {
                xaq[(size_t)row * RANK + r] = aq[r];
                xav[(size_t)row * RANK + r] = av[r];
            }
        }
    }
}

// ---------------- 256x256 8-wave 8-phase GEMM ----------------
// LDS: 2 buffers x (A 256x64 + B 256x64) bf16 = 128 KiB, XOR-swizzled.
// Fragment map (progressive half consumption):
//   A m-frag f: rows wr*64 + (f&3)*16 + (f>>2)*128  -> f<4 in A-half0
//   B n-frag n: rows wc*16 + n*64                   -> n<2 in B-half0
// Staging order per tile: A0,B0,B1,A1 of tile t+1 (2 loads each).
// vmcnt ledger (per wave, 2 loads/phase): boundary invariant = 4 outstanding
// {B1(t),A1(t)}; ph0 issue->6, wait4 retires B1; ph1 issue->6, wait4 retires
// A1; ph2 issue->6, no wait; ph3 issue->8, wait4 retires A0,B0. Tail (tile 15,
// no staging): wait2 after ph0 retires B1(15); wait0 after ph1 retires A1(15).

__device__ __forceinline__ void stage_half(const u16* __restrict__ mat, int row0, int tk,
                                           u16* dst, int wave, int lane) {
    const int lrow = lane >> 3;
    const int g    = (lane & 7) ^ lrow;          // pre-swizzled 16B group
    const u16* gp = mat + (size_t)(row0 + wave * 8 + lrow) * DIM + tk + g * 8;
    u16* lp = dst + wave * 8 * 64;               // wave-uniform LDS base
    gl2lds16(gp, lp);
    gl2lds16(gp + (size_t)64 * DIM, lp + 64 * 64);
}

__device__ __forceinline__ void ds_read_A(const u16* sA, int wr, int lane,
                                          int kx0, int kx1, int mh, short8 (&a)[4][2]) {
    #pragma unroll
    for (int f = 0; f < 4; ++f) {
        const int row = wr * 64 + f * 16 + mh * 128 + (lane & 15);
        a[f][0] = *reinterpret_cast<const short8*>(sA + row * 64 + kx0);
        a[f][1] = *reinterpret_cast<const short8*>(sA + row * 64 + kx1);
    }
}
__device__ __forceinline__ void ds_read_B(const u16* sB, int wc, int lane,
                                          int kx0, int kx1, int nh, short8 (&b)[2][2]) {
    #pragma unroll
    for (int f = 0; f < 2; ++f) {
        const int row = wc * 16 + (nh * 2 + f) * 64 + (lane & 15);
        b[f][0] = *reinterpret_cast<const short8*>(sB + row * 64 + kx0);
        b[f][1] = *reinterpret_cast<const short8*>(sB + row * 64 + kx1);
    }
}

template <int MH, int NH>
__device__ __forceinline__ void mfma_quad(const short8 (&a)[4][2], const short8 (&b)[2][2],
                                          f32x4 (&acc)[8][4]) {
    #pragma unroll
    for (int ks = 0; ks < 2; ++ks)
        #pragma unroll
        for (int f = 0; f < 4; ++f)
            #pragma unroll
            for (int g = 0; g < 2; ++g)
                acc[MH * 4 + f][NH * 2 + g] = __builtin_amdgcn_mfma_f32_16x16x32_bf16(
                    a[f][ks], b[g][ks], acc[MH * 4 + f][NH * 2 + g], 0, 0, 0);
}

#define PHASE_MFMA(MH, NH)                              \
    do {                                                \
        BAR();                                          \
        SCHED0();                                       \
        __builtin_amdgcn_s_setprio(1);                  \
        mfma_quad<MH, NH>(a, b, acc);                   \
        __builtin_amdgcn_s_setprio(0);                  \
        SCHED0();                                       \
    } while (0)

__global__ __launch_bounds__(512, 2) void k_gemm(const u16* __restrict__ Xc,
                                                 const u16* __restrict__ Wc,
                                                 const float* __restrict__ bias,
                                                 const float* __restrict__ Bq_pool,
                                                 const float* __restrict__ Bv_pool,
                                                 const float* __restrict__ xaq,
                                                 const float* __restrict__ xav,
                                                 const int* __restrict__ idx,
                                                 float* __restrict__ out) {
    extern __shared__ u16 lds[];               // 128 KiB
    const int tid  = threadIdx.x;
    const int lane = tid & 63, wave = tid >> 6;
    const int wr = wave >> 2, wc = wave & 3;   // 2M x 4N wave grid

    // bijective XCD swizzle (nwg=1536, 1536%8==0)
    const int orig = blockIdx.x;
    const int wg   = (orig & 7) * 192 + (orig >> 3);
    const int bn   = wg % 12;
    const int bm   = wg / 12;
    const int m0 = bm * 256, n0 = bn * 256;

    const int kx0 = (((lane >> 4)    ) ^ (lane & 7)) * 8;
    const int kx1 = (((lane >> 4) + 4) ^ (lane & 7)) * 8;

    f32x4 acc[8][4] = {};

    // prologue: tile 0 fully into buffer 0
    stage_half(Xc, m0,       0, lds,                    wave, lane);
    stage_half(Xc, m0 + 128, 0, lds + 128 * 64,         wave, lane);
    stage_half(Wc, n0,       0, lds + 16384,            wave, lane);
    stage_half(Wc, n0 + 128, 0, lds + 16384 + 128 * 64, wave, lane);
    WAITV0(); BAR();

    #pragma unroll 1
    for (int t = 0; t < 15; ++t) {
        const u16* sA = lds + (t & 1) * 32768;
        const u16* sB = sA + 16384;
        u16* wA = lds + ((t + 1) & 1) * 32768;
        u16* wB = wA + 16384;
        const int tk1 = (t + 1) * 64;
        short8 a[4][2], b[2][2];

        // ---- phase 0: quad(0,0); stage A0(t+1) ----
        ds_read_A(sA, wr, lane, kx0, kx1, 0, a);
        ds_read_B(sB, wc, lane, kx0, kx1, 0, b);
        stage_half(Xc, m0, tk1, wA, wave, lane);
        PHASE_MFMA(0, 0);
        WAITV4(); BAR();

        // ---- phase 1: quad(0,1); stage B0(t+1) ----
        ds_read_B(sB, wc, lane, kx0, kx1, 1, b);
        stage_half(Wc, n0, tk1, wB, wave, lane);
        PHASE_MFMA(0, 1);
        WAITV4(); BAR();

        // ---- phase 2: quad(1,0); stage B1(t+1) ----
        ds_read_A(sA, wr, lane, kx0, kx1, 1, a);
        ds_read_B(sB, wc, lane, kx0, kx1, 0, b);
        stage_half(Wc, n0 + 128, tk1, wB + 128 * 64, wave, lane);
        PHASE_MFMA(1, 0);
        BAR();

        // ---- phase 3: quad(1,1); stage A1(t+1) ----
        ds_read_B(sB, wc, lane, kx0, kx1, 1, b);
        stage_half(Xc, m0 + 128, tk1, wA + 128 * 64, wave, lane);
        PHASE_MFMA(1, 1);
        WAITV4(); BAR();
    }

    // ---- peeled tail: tile 15, no staging; drain schedule ----
    {
        const u16* sA = lds + 32768;   // 15 & 1 == 1
        const u16* sB = sA + 16384;
        short8 a[4][2], b[2][2];

        ds_read_A(sA, wr, lane, kx0, kx1, 0, a);
        ds_read_B(sB, wc, lane, kx0, kx1, 0, b);
        PHASE_MFMA(0, 0);
        WAITV2(); BAR();               // retire B1(15) before reading B-half1

        ds_read_B(sB, wc, lane, kx0, kx1, 1, b);
        PHASE_MFMA(0, 1);
        WAITV0(); BAR();               // retire A1(15) before reading A-half1

        ds_read_A(sA, wr, lane, kx0, kx1, 1, a);
        ds_read_B(sB, wc, lane, kx0, kx1, 0, b);
        PHASE_MFMA(1, 0);
        BAR();

        ds_read_B(sB, wc, lane, kx0, kx1, 1, b);
        PHASE_MFMA(1, 1);
    }

    // ---------------- epilogue: bias + LoRA + store ----------------
    const int p = idx[m0 >> 12];
    const float* Bmat = nullptr;
    const float* xa   = nullptr;
    if (n0 < DIM)           { Bmat = Bq_pool + (size_t)p * (RANK * DIM); xa = xaq; }
    else if (n0 >= 2 * DIM) { Bmat = Bv_pool + (size_t)p * (RANK * DIM); xa = xav; }

    const int cn   = wc * 16 + (lane & 15);      // col within 256-block, + ni*64
    const int slab = n0 % DIM;
    float bcol[4];
    float bq[4][8];
    #pragma unroll
    for (int ni = 0; ni < 4; ++ni) {
        bcol[ni] = bias[n0 + cn + ni * 64];
        if (Bmat) {
            #pragma unroll
            for (int r = 0; r < 8; ++r)
                bq[ni][r] = Bmat[r * DIM + slab + cn + ni * 64];
        }
    }
    #pragma unroll
    for (int mi = 0; mi < 8; ++mi) {
        const int rb = m0 + wr * 64 + (mi & 3) * 16 + (mi >> 2) * 128 + (lane >> 4) * 4;
        #pragma unroll
        for (int v = 0; v < 4; ++v) {
            const size_t row = (size_t)(rb + v);
            float xr[8];
            if (Bmat) {
                const float4* q = reinterpret_cast<const float4*>(xa + row * RANK);
                float4 x0 = q[0], x1 = q[1];
                xr[0] = x0.x; xr[1] = x0.y; xr[2] = x0.z; xr[3] = x0.w;
                xr[4] = x1.x; xr[5] = x1.y; xr[6] = x1.z; xr[7] = x1.w;
            }
            #pragma unroll
            for (int ni = 0; ni < 4; ++ni) {
                float val = acc[mi][ni][v] + bcol[ni];
                if (Bmat) {
                    float s = 0.f;
                    #pragma unroll
                    for (int r = 0; r < 8; ++r) s += xr[r] * bq[ni][r];
                    val += s;   // SCALE = 1.0
                }
                out[row * ODIM + (size_t)(n0 + cn + ni * 64)] = val;
            }
        }
    }
}

extern "C" void kernel_launch(void* const* d_in, const int* in_sizes, int n_in,
                              void* d_out, int out_size, void* d_ws, size_t ws_size,
                              hipStream_t stream) {
    const float* x      = (const float*)d_in[0];
    const float* weight = (const float*)d_in[1];
    const float* bias   = (const float*)d_in[2];
    const float* Aq     = (const float*)d_in[3];
    const float* Bq     = (const float*)d_in[4];
    const float* Av     = (const float*)d_in[5];
    const float* Bv     = (const float*)d_in[6];
    const int*   idx    = (const int*)d_in[7];
    float* out = (float*)d_out;

    u16*  Xc  = (u16*)d_ws;
    u16*  Wc  = Xc + (size_t)MROWS * DIM;
    float* xaq = (float*)(Wc + (size_t)ODIM * DIM);
    float* xav = xaq + (size_t)MROWS * RANK;

    hipFuncSetAttribute(reinterpret_cast<const void*>(k_gemm),
                        hipFuncAttributeMaxDynamicSharedMemorySize, 131072);

    k_convert<<<2048, 256, 0, stream>>>(x, Xc, MROWS * DIM);
    k_convert<<<1536, 256, 0, stream>>>(weight, Wc, ODIM * DIM);
    k_lora_xa<<<MROWS / 32, 256, 0, stream>>>(Xc, Aq, Av, idx, xaq, xav);
    k_gemm<<<1536, 512, 131072, stream>>>(Xc, Wc, bias, Bq, Bv, xaq, xav, idx, out);
}

// Round 5
// 330.642 us; speedup vs baseline: 1.2082x; 1.2082x over previous
//
#include <hip/hip_runtime.h>
#include <hip/hip_bf16.h>
#include <stdint.h>

#define DIM   1024
#define ODIM  3072
#define MROWS 32768   // B(8) * N(4096)
#define RANK  8

typedef unsigned short u16;
typedef __attribute__((ext_vector_type(8))) short short8;
typedef __attribute__((ext_vector_type(8))) unsigned short u16x8;
typedef __attribute__((ext_vector_type(4))) unsigned short u16x4;
typedef __attribute__((ext_vector_type(4))) float f32x4;

__device__ __forceinline__ u16 f2bf(float f) {
    uint32_t u = __float_as_uint(f);
    u += 0x7fffu + ((u >> 16) & 1u);   // RNE
    return (u16)(u >> 16);
}

__device__ __forceinline__ void gl2lds16(const void* g, void* l) {
    __builtin_amdgcn_global_load_lds(
        (const __attribute__((address_space(1))) void*)(uintptr_t)g,
        (__attribute__((address_space(3))) void*)(uint32_t)(uintptr_t)l,
        16, 0, 0);
}

#define BAR()    do { asm volatile("" ::: "memory"); __builtin_amdgcn_s_barrier(); asm volatile("" ::: "memory"); } while (0)
#define WAITV10() asm volatile("s_waitcnt vmcnt(10)" ::: "memory")
#define WAITV8()  asm volatile("s_waitcnt vmcnt(8)" ::: "memory")
#define WAITV4()  asm volatile("s_waitcnt vmcnt(4)" ::: "memory")
#define WAITV2()  asm volatile("s_waitcnt vmcnt(2)" ::: "memory")
#define WAITV0()  asm volatile("s_waitcnt vmcnt(0)" ::: "memory")
#define SCHED0()  __builtin_amdgcn_sched_barrier(0)

// ---------------- f32 -> bf16 conversion ----------------
__global__ __launch_bounds__(256) void k_convert(const float* __restrict__ src,
                                                 u16* __restrict__ dst, int n) {
    const int stride = gridDim.x * blockDim.x;
    for (int t = blockIdx.x * blockDim.x + threadIdx.x; t * 8 < n; t += stride) {
        const int i = t * 8;
        float4 a = *reinterpret_cast<const float4*>(src + i);
        float4 b = *reinterpret_cast<const float4*>(src + i + 4);
        u16x8 o;
        o[0] = f2bf(a.x); o[1] = f2bf(a.y); o[2] = f2bf(a.z); o[3] = f2bf(a.w);
        o[4] = f2bf(b.x); o[5] = f2bf(b.y); o[6] = f2bf(b.z); o[7] = f2bf(b.w);
        *reinterpret_cast<u16x8*>(dst + i) = o;
    }
}

// ---------------- Wmod[b] = W_slab + (A[idx_b] @ B[idx_b])^T, bf16 ----------------
// delta[o][i] = sum_r A[i][r] * B[r][o]; SCALE = 1.0.
// grid: 1024 blocks = b(8) x s(2: q,v) x og(64 groups of 16 o-rows); 256 thr.
// thread t owns i-range [4t, 4t+3] for all 16 rows; A[i][0..7] cached in regs.
__global__ __launch_bounds__(256) void k_build(const float* __restrict__ W,
                                               const float* __restrict__ Aq_pool,
                                               const float* __restrict__ Bq_pool,
                                               const float* __restrict__ Av_pool,
                                               const float* __restrict__ Bv_pool,
                                               const int* __restrict__ idx,
                                               u16* __restrict__ Wmq,
                                               u16* __restrict__ Wmv) {
    const int b  = blockIdx.x >> 7;
    const int s  = (blockIdx.x >> 6) & 1;
    const int og = blockIdx.x & 63;
    const int p  = idx[b];
    const float* A  = (s ? Av_pool : Aq_pool) + (size_t)p * DIM * RANK;
    const float* Bp = (s ? Bv_pool : Bq_pool) + (size_t)p * RANK * DIM;
    const float* Ws = W + (size_t)(s ? 2048 : 0) * DIM;
    u16* dst = (s ? Wmv : Wmq) + (size_t)b * DIM * DIM;

    const int t  = threadIdx.x;
    const int i0 = t * 4;
    float a[4][8];
    #pragma unroll
    for (int ii = 0; ii < 4; ++ii) {
        float4 a0 = reinterpret_cast<const float4*>(A + (size_t)(i0 + ii) * RANK)[0];
        float4 a1 = reinterpret_cast<const float4*>(A + (size_t)(i0 + ii) * RANK)[1];
        a[ii][0] = a0.x; a[ii][1] = a0.y; a[ii][2] = a0.z; a[ii][3] = a0.w;
        a[ii][4] = a1.x; a[ii][5] = a1.y; a[ii][6] = a1.z; a[ii][7] = a1.w;
    }
    for (int r = 0; r < 16; ++r) {
        const int o = og * 16 + r;
        float bv[8];
        #pragma unroll
        for (int rr = 0; rr < 8; ++rr) bv[rr] = Bp[(size_t)rr * DIM + o];
        float4 w = *reinterpret_cast<const float4*>(Ws + (size_t)o * DIM + i0);
        float v[4] = {w.x, w.y, w.z, w.w};
        u16x4 ov;
        #pragma unroll
        for (int ii = 0; ii < 4; ++ii) {
            float d = 0.f;
            #pragma unroll
            for (int rr = 0; rr < 8; ++rr) d += a[ii][rr] * bv[rr];
            ov[ii] = f2bf(v[ii] + d);
        }
        *reinterpret_cast<u16x4*>(dst + (size_t)o * DIM + i0) = ov;
    }
}

// ---------------- 256x256 8-wave 8-phase GEMM (frag-hold, deep prefetch) ---------
// LDS: 2 buffers x (A 256x64 + B 256x64) bf16 = 128 KiB, XOR-swizzled
// (16B group g of row r stored at g^(r&7), via pre-swizzled global src).
// Fragment map: A m-frag f: rows wr*64+(f&3)*16+(f>>2)*128 (f<4 in A-half0);
//               B n-frag n: rows wc*16+n*64 (n<2 in B-half0).
// Per K-tile: ph0 reads Ah0(8)+Bh0(4) & issues ALL 8 next-tile loads
// (A0,B0,B1,A1); ph1 reads Bh1(4); ph2 reads Ah1(8); ph3 pure MFMA.
// B-frags held in regs across the tile -> 24 ds_read_b128/wave/tile.
// vmcnt ledger (2 loads/half, boundary invariant {B1(t),A1(t)}=4):
//   ph0 end: 12 out -> vmcnt(10) retires B1(t) (needed ph1)
//   ph1 end: 10 out -> vmcnt(8)  retires A1(t) (needed ph2)
//   ph3 end:  8 out -> vmcnt(4)  retires A0,B0(t+1) (needed ph0 of t+1)
// Prefetch distance: 4-6 phases (~800-1200 cyc) >= HBM latency.
// Tail (tile 15, no staging): vmcnt(2) after ph0, vmcnt(0) after ph1.

__device__ __forceinline__ void stage_half(const u16* __restrict__ mat, int row0, int tk,
                                           u16* dst, int wave, int lane) {
    const int lrow = lane >> 3;
    const int g    = (lane & 7) ^ lrow;          // pre-swizzled 16B group
    const u16* gp = mat + (size_t)(row0 + wave * 8 + lrow) * DIM + tk + g * 8;
    u16* lp = dst + wave * 8 * 64;               // wave-uniform LDS base
    gl2lds16(gp, lp);
    gl2lds16(gp + (size_t)64 * DIM, lp + 64 * 64);
}

__device__ __forceinline__ void ds_read_A(const u16* sA, int wr, int lane,
                                          int kx0, int kx1, int mh, short8 (&a)[4][2]) {
    #pragma unroll
    for (int f = 0; f < 4; ++f) {
        const int row = wr * 64 + f * 16 + mh * 128 + (lane & 15);
        a[f][0] = *reinterpret_cast<const short8*>(sA + row * 64 + kx0);
        a[f][1] = *reinterpret_cast<const short8*>(sA + row * 64 + kx1);
    }
}
__device__ __forceinline__ void ds_read_B(const u16* sB, int wc, int lane,
                                          int kx0, int kx1, int nh, short8 (&b)[2][2]) {
    #pragma unroll
    for (int f = 0; f < 2; ++f) {
        const int row = wc * 16 + (nh * 2 + f) * 64 + (lane & 15);
        b[f][0] = *reinterpret_cast<const short8*>(sB + row * 64 + kx0);
        b[f][1] = *reinterpret_cast<const short8*>(sB + row * 64 + kx1);
    }
}

template <int MH, int NH>
__device__ __forceinline__ void mfma_quad(const short8 (&a)[4][2], const short8 (&b)[2][2],
                                          f32x4 (&acc)[8][4]) {
    #pragma unroll
    for (int ks = 0; ks < 2; ++ks)
        #pragma unroll
        for (int f = 0; f < 4; ++f)
            #pragma unroll
            for (int g = 0; g < 2; ++g)
                acc[MH * 4 + f][NH * 2 + g] = __builtin_amdgcn_mfma_f32_16x16x32_bf16(
                    a[f][ks], b[g][ks], acc[MH * 4 + f][NH * 2 + g], 0, 0, 0);
}

#define PHASE(MH, NH, BREG)                             \
    do {                                                \
        BAR();                                          \
        SCHED0();                                       \
        __builtin_amdgcn_s_setprio(1);                  \
        mfma_quad<MH, NH>(a, BREG, acc);                \
        __builtin_amdgcn_s_setprio(0);                  \
        SCHED0();                                       \
    } while (0)

__global__ __launch_bounds__(512, 2) void k_gemm(const u16* __restrict__ Xc,
                                                 const u16* __restrict__ Wk,
                                                 const u16* __restrict__ Wmq,
                                                 const u16* __restrict__ Wmv,
                                                 const float* __restrict__ bias,
                                                 float* __restrict__ out) {
    extern __shared__ u16 lds[];               // 128 KiB
    const int tid  = threadIdx.x;
    const int lane = tid & 63, wave = tid >> 6;
    const int wr = wave >> 2, wc = wave & 3;   // 2M x 4N wave grid

    // bijective XCD swizzle (nwg=1536, 1536%8==0)
    const int orig = blockIdx.x;
    const int wg   = (orig & 7) * 192 + (orig >> 3);
    const int bn   = wg % 12;
    const int bm   = wg / 12;
    const int m0 = bm * 256, n0 = bn * 256;
    const int batch = m0 >> 12;

    // B-operand: per-batch LoRA-folded weight for q/v slabs, shared for k
    const u16* Bmat;
    int nc;   // column offset within the slab
    if (n0 < DIM)           { Bmat = Wmq + (size_t)batch * DIM * DIM; nc = n0; }
    else if (n0 < 2 * DIM)  { Bmat = Wk;                              nc = n0 - DIM; }
    else                    { Bmat = Wmv + (size_t)batch * DIM * DIM; nc = n0 - 2 * DIM; }

    const int kx0 = (((lane >> 4)    ) ^ (lane & 7)) * 8;
    const int kx1 = (((lane >> 4) + 4) ^ (lane & 7)) * 8;

    f32x4 acc[8][4] = {};

    // prologue: tile 0 fully into buffer 0
    stage_half(Xc,   m0,       0, lds,                    wave, lane);
    stage_half(Bmat, nc,       0, lds + 16384,            wave, lane);
    stage_half(Bmat, nc + 128, 0, lds + 16384 + 128 * 64, wave, lane);
    stage_half(Xc,   m0 + 128, 0, lds + 128 * 64,         wave, lane);
    WAITV0(); BAR();

    #pragma unroll 1
    for (int t = 0; t < 15; ++t) {
        const u16* sA = lds + (t & 1) * 32768;
        const u16* sB = sA + 16384;
        u16* wA = lds + ((t + 1) & 1) * 32768;
        u16* wB = wA + 16384;
        const int tk1 = (t + 1) * 64;
        short8 a[4][2], b0[2][2], b1[2][2];

        // ---- phase 0: read Ah0+Bh0; issue ALL next-tile loads; quad(0,0) ----
        ds_read_A(sA, wr, lane, kx0, kx1, 0, a);
        ds_read_B(sB, wc, lane, kx0, kx1, 0, b0);
        stage_half(Xc,   m0,       tk1, wA,            wave, lane);   // A0
        stage_half(Bmat, nc,       tk1, wB,            wave, lane);   // B0
        stage_half(Bmat, nc + 128, tk1, wB + 128 * 64, wave, lane);   // B1
        stage_half(Xc,   m0 + 128, tk1, wA + 128 * 64, wave, lane);   // A1
        PHASE(0, 0, b0);
        WAITV10(); BAR();

        // ---- phase 1: read Bh1; quad(0,1) ----
        ds_read_B(sB, wc, lane, kx0, kx1, 1, b1);
        PHASE(0, 1, b1);
        WAITV8(); BAR();

        // ---- phase 2: read Ah1; quad(1,0) reuses b0 ----
        ds_read_A(sA, wr, lane, kx0, kx1, 1, a);
        PHASE(1, 0, b0);
        BAR();

        // ---- phase 3: pure MFMA; quad(1,1) reuses b1 ----
        PHASE(1, 1, b1);
        WAITV4(); BAR();
    }

    // ---- peeled tail: tile 15, no staging; drain schedule ----
    {
        const u16* sA = lds + 32768;   // 15 & 1 == 1
        const u16* sB = sA + 16384;
        short8 a[4][2], b0[2][2], b1[2][2];

        ds_read_A(sA, wr, lane, kx0, kx1, 0, a);
        ds_read_B(sB, wc, lane, kx0, kx1, 0, b0);
        PHASE(0, 0, b0);
        WAITV2(); BAR();               // retire B1(15) before reading B-half1

        ds_read_B(sB, wc, lane, kx0, kx1, 1, b1);
        PHASE(0, 1, b1);
        WAITV0(); BAR();               // retire A1(15) before reading A-half1

        ds_read_A(sA, wr, lane, kx0, kx1, 1, a);
        PHASE(1, 0, b0);
        BAR();

        PHASE(1, 1, b1);
    }

    // ---------------- epilogue: bias + store ----------------
    const int cn = wc * 16 + (lane & 15);      // col within 256-block, + ni*64
    float bcol[4];
    #pragma unroll
    for (int ni = 0; ni < 4; ++ni) bcol[ni] = bias[n0 + cn + ni * 64];
    #pragma unroll
    for (int mi = 0; mi < 8; ++mi) {
        const int rb = m0 + wr * 64 + (mi & 3) * 16 + (mi >> 2) * 128 + (lane >> 4) * 4;
        #pragma unroll
        for (int v = 0; v < 4; ++v) {
            const size_t row = (size_t)(rb + v);
            #pragma unroll
            for (int ni = 0; ni < 4; ++ni)
                out[row * ODIM + (size_t)(n0 + cn + ni * 64)] = acc[mi][ni][v] + bcol[ni];
        }
    }
}

extern "C" void kernel_launch(void* const* d_in, const int* in_sizes, int n_in,
                              void* d_out, int out_size, void* d_ws, size_t ws_size,
                              hipStream_t stream) {
    const float* x      = (const float*)d_in[0];
    const float* weight = (const float*)d_in[1];
    const float* bias   = (const float*)d_in[2];
    const float* Aq     = (const float*)d_in[3];
    const float* Bq     = (const float*)d_in[4];
    const float* Av     = (const float*)d_in[5];
    const float* Bv     = (const float*)d_in[6];
    const int*   idx    = (const int*)d_in[7];
    float* out = (float*)d_out;

    // workspace: Xc(64MB) | Wk(2MB) | Wmq(16MB) | Wmv(16MB) = 98MB
    u16* Xc  = (u16*)d_ws;
    u16* Wk  = Xc + (size_t)MROWS * DIM;
    u16* Wmq = Wk + (size_t)DIM * DIM;
    u16* Wmv = Wmq + (size_t)8 * DIM * DIM;

    hipFuncSetAttribute(reinterpret_cast<const void*>(k_gemm),
                        hipFuncAttributeMaxDynamicSharedMemorySize, 131072);

    k_convert<<<2048, 256, 0, stream>>>(x, Xc, MROWS * DIM);
    k_convert<<<512, 256, 0, stream>>>(weight + (size_t)DIM * DIM, Wk, DIM * DIM);
    k_build<<<1024, 256, 0, stream>>>(weight, Aq, Bq, Av, Bv, idx, Wmq, Wmv);
    k_gemm<<<1536, 512, 131072, stream>>>(Xc, Wk, Wmq, Wmv, bias, out);
}

// Round 6
// 324.921 us; speedup vs baseline: 1.2294x; 1.0176x over previous
//
#include <hip/hip_runtime.h>
#include <hip/hip_bf16.h>
#include <stdint.h>

#define DIM   1024
#define ODIM  3072
#define MROWS 32768   // B(8) * N(4096)
#define RANK  8
#define BK    32

typedef unsigned short u16;
typedef __attribute__((ext_vector_type(8))) short short8;
typedef __attribute__((ext_vector_type(8))) unsigned short u16x8;
typedef __attribute__((ext_vector_type(4))) unsigned short u16x4;
typedef __attribute__((ext_vector_type(4))) float f32x4;

__device__ __forceinline__ u16 f2bf(float f) {
    uint32_t u = __float_as_uint(f);
    u += 0x7fffu + ((u >> 16) & 1u);   // RNE
    return (u16)(u >> 16);
}

__device__ __forceinline__ void gl2lds16(const void* g, void* l) {
    __builtin_amdgcn_global_load_lds(
        (const __attribute__((address_space(1))) void*)(uintptr_t)g,
        (__attribute__((address_space(3))) void*)(uint32_t)(uintptr_t)l,
        16, 0, 0);
}

#define BAR()    do { asm volatile("" ::: "memory"); __builtin_amdgcn_s_barrier(); asm volatile("" ::: "memory"); } while (0)
#define WAITV2() asm volatile("s_waitcnt vmcnt(2)" ::: "memory")
#define WAITV0() asm volatile("s_waitcnt vmcnt(0)" ::: "memory")

// ---------------- f32 -> bf16 conversion ----------------
__global__ __launch_bounds__(256) void k_convert(const float* __restrict__ src,
                                                 u16* __restrict__ dst, int n) {
    const int stride = gridDim.x * blockDim.x;
    for (int t = blockIdx.x * blockDim.x + threadIdx.x; t * 8 < n; t += stride) {
        const int i = t * 8;
        float4 a = *reinterpret_cast<const float4*>(src + i);
        float4 b = *reinterpret_cast<const float4*>(src + i + 4);
        u16x8 o;
        o[0] = f2bf(a.x); o[1] = f2bf(a.y); o[2] = f2bf(a.z); o[3] = f2bf(a.w);
        o[4] = f2bf(b.x); o[5] = f2bf(b.y); o[6] = f2bf(b.z); o[7] = f2bf(b.w);
        *reinterpret_cast<u16x8*>(dst + i) = o;
    }
}

// ---------------- Wmod[b] = W_slab + (A[idx_b] @ B[idx_b])^T, bf16 ----------------
__global__ __launch_bounds__(256) void k_build(const float* __restrict__ W,
                                               const float* __restrict__ Aq_pool,
                                               const float* __restrict__ Bq_pool,
                                               const float* __restrict__ Av_pool,
                                               const float* __restrict__ Bv_pool,
                                               const int* __restrict__ idx,
                                               u16* __restrict__ Wmq,
                                               u16* __restrict__ Wmv) {
    const int b  = blockIdx.x >> 7;
    const int s  = (blockIdx.x >> 6) & 1;
    const int og = blockIdx.x & 63;
    const int p  = idx[b];
    const float* A  = (s ? Av_pool : Aq_pool) + (size_t)p * DIM * RANK;
    const float* Bp = (s ? Bv_pool : Bq_pool) + (size_t)p * RANK * DIM;
    const float* Ws = W + (size_t)(s ? 2048 : 0) * DIM;
    u16* dst = (s ? Wmv : Wmq) + (size_t)b * DIM * DIM;

    const int t  = threadIdx.x;
    const int i0 = t * 4;
    float a[4][8];
    #pragma unroll
    for (int ii = 0; ii < 4; ++ii) {
        float4 a0 = reinterpret_cast<const float4*>(A + (size_t)(i0 + ii) * RANK)[0];
        float4 a1 = reinterpret_cast<const float4*>(A + (size_t)(i0 + ii) * RANK)[1];
        a[ii][0] = a0.x; a[ii][1] = a0.y; a[ii][2] = a0.z; a[ii][3] = a0.w;
        a[ii][4] = a1.x; a[ii][5] = a1.y; a[ii][6] = a1.z; a[ii][7] = a1.w;
    }
    for (int r = 0; r < 16; ++r) {
        const int o = og * 16 + r;
        float bv[8];
        #pragma unroll
        for (int rr = 0; rr < 8; ++rr) bv[rr] = Bp[(size_t)rr * DIM + o];
        float4 w = *reinterpret_cast<const float4*>(Ws + (size_t)o * DIM + i0);
        float v[4] = {w.x, w.y, w.z, w.w};
        u16x4 ov;
        #pragma unroll
        for (int ii = 0; ii < 4; ++ii) {
            float d = 0.f;
            #pragma unroll
            for (int rr = 0; rr < 8; ++rr) d += a[ii][rr] * bv[rr];
            ov[ii] = f2bf(v[ii] + d);
        }
        *reinterpret_cast<u16x4*>(dst + (size_t)o * DIM + i0) = ov;
    }
}

// ---------------- 256x256 16-wave triple-buffered GEMM, BK=32 ----------------
// 16 waves (4Mx4N), per-wave 64x64 (acc 64 f32 -> 4 waves/SIMD at <=128 regs).
// LDS: 3 buffers x (A 256x32 + B 256x32) bf16 = 96 KiB.
// Swizzle (64B rows, 4x16B groups): dest(r,g) holds src group g^s(r),
// s(r)=(r&3)^((r>>2)&3); staged via pre-swizzled global source (rule #21).
// Read: kx = ((lane>>4) ^ (lane&3) ^ ((lane>>2)&3)) * 8  (uniform across frags
// since all frag rows are multiples of 16). Per-16-lane beat: 2-way = free.
// Schedule per tile t: stage(t+2, 2 loads) -> 8 ds_read -> 16 MFMA(setprio) ->
// vmcnt(2) (retires tile t+1's loads, keeps t+2 in flight) -> ONE barrier.
// Race-free: buffer written at t was last read at t-1, behind that barrier.
// Prefetch distance = 2 full tiles >> HBM latency; never drains in main loop.

__device__ __forceinline__ void stage(const u16* __restrict__ Xc,
                                      const u16* __restrict__ Bm,
                                      int m0, int nc, int tk,
                                      u16* buf, int wave, int lane) {
    const int rl = lane >> 2;                       // row within wave's 16-row slab
    const int gs = (lane & 3) ^ ((lane >> 2) & 3) ^ ((lane >> 4) & 3);
    const u16* ga = Xc + (size_t)(m0 + wave * 16 + rl) * DIM + tk + gs * 8;
    const u16* gb = Bm + (size_t)(nc + wave * 16 + rl) * DIM + tk + gs * 8;
    gl2lds16(ga, buf + wave * 512);
    gl2lds16(gb, buf + 8192 + wave * 512);
}

__device__ __forceinline__ void tile_mfma(const u16* __restrict__ buf,
                                          int wr, int wc, int lane, int kx,
                                          f32x4 (&acc)[4][4]) {
    short8 a[4], b[4];
    #pragma unroll
    for (int f = 0; f < 4; ++f)
        a[f] = *reinterpret_cast<const short8*>(buf + (wr * 64 + f * 16 + (lane & 15)) * 32 + kx);
    #pragma unroll
    for (int n = 0; n < 4; ++n)
        b[n] = *reinterpret_cast<const short8*>(buf + 8192 + (wc * 64 + n * 16 + (lane & 15)) * 32 + kx);
    __builtin_amdgcn_s_setprio(1);
    #pragma unroll
    for (int f = 0; f < 4; ++f)
        #pragma unroll
        for (int n = 0; n < 4; ++n)
            acc[f][n] = __builtin_amdgcn_mfma_f32_16x16x32_bf16(a[f], b[n], acc[f][n], 0, 0, 0);
    __builtin_amdgcn_s_setprio(0);
}

__global__ __launch_bounds__(1024, 4) void k_gemm(const u16* __restrict__ Xc,
                                                  const u16* __restrict__ Wk,
                                                  const u16* __restrict__ Wmq,
                                                  const u16* __restrict__ Wmv,
                                                  const float* __restrict__ bias,
                                                  const int* __restrict__ idx,
                                                  float* __restrict__ out) {
    extern __shared__ u16 lds[];               // 96 KiB: 3 x 16384 u16
    const int tid  = threadIdx.x;
    const int lane = tid & 63, wave = tid >> 6;
    const int wr = wave >> 2, wc = wave & 3;   // 4M x 4N wave grid, 64x64 each

    // bijective XCD swizzle (nwg=1536, 1536%8==0)
    const int orig = blockIdx.x;
    const int wg   = (orig & 7) * 192 + (orig >> 3);
    const int bn   = wg % 12;
    const int bm   = wg / 12;
    const int m0 = bm * 256, n0 = bn * 256;
    const int batch = m0 >> 12;

    const u16* Bmat;
    int nc;
    if (n0 < DIM)           { Bmat = Wmq + (size_t)batch * DIM * DIM; nc = n0; }
    else if (n0 < 2 * DIM)  { Bmat = Wk;                              nc = n0 - DIM; }
    else                    { Bmat = Wmv + (size_t)batch * DIM * DIM; nc = n0 - 2 * DIM; }

    const int kx = ((lane >> 4) ^ (lane & 3) ^ ((lane >> 2) & 3)) * 8;

    u16* b0 = lds;
    u16* b1 = lds + 16384;
    u16* b2 = lds + 32768;

    f32x4 acc[4][4] = {};

    // prologue: stage tiles 0,1
    stage(Xc, Bmat, m0, nc, 0,  b0, wave, lane);
    stage(Xc, Bmat, m0, nc, BK, b1, wave, lane);
    WAITV2(); BAR();                           // tile 0 landed (all waves)

    #pragma unroll 1
    for (int t3 = 0; t3 < 30; t3 += 3) {
        stage(Xc, Bmat, m0, nc, (t3 + 2) * BK, b2, wave, lane);
        tile_mfma(b0, wr, wc, lane, kx, acc);
        WAITV2(); BAR();

        stage(Xc, Bmat, m0, nc, (t3 + 3) * BK, b0, wave, lane);
        tile_mfma(b1, wr, wc, lane, kx, acc);
        WAITV2(); BAR();

        stage(Xc, Bmat, m0, nc, (t3 + 4) * BK, b1, wave, lane);
        tile_mfma(b2, wr, wc, lane, kx, acc);
        WAITV2(); BAR();
    }
    // t = 30: read b0, no stage; drain tile 31's loads
    tile_mfma(b0, wr, wc, lane, kx, acc);
    WAITV0(); BAR();
    // t = 31: read b1
    tile_mfma(b1, wr, wc, lane, kx, acc);

    // ---------------- epilogue: bias + store ----------------
    const int cn = wc * 64 + (lane & 15);
    float bcol[4];
    #pragma unroll
    for (int n = 0; n < 4; ++n) bcol[n] = bias[n0 + cn + n * 16];
    #pragma unroll
    for (int f = 0; f < 4; ++f) {
        const int rb = m0 + wr * 64 + f * 16 + (lane >> 4) * 4;
        #pragma unroll
        for (int v = 0; v < 4; ++v) {
            const size_t row = (size_t)(rb + v);
            #pragma unroll
            for (int n = 0; n < 4; ++n)
                out[row * ODIM + (size_t)(n0 + cn + n * 16)] = acc[f][n][v] + bcol[n];
        }
    }
}

extern "C" void kernel_launch(void* const* d_in, const int* in_sizes, int n_in,
                              void* d_out, int out_size, void* d_ws, size_t ws_size,
                              hipStream_t stream) {
    const float* x      = (const float*)d_in[0];
    const float* weight = (const float*)d_in[1];
    const float* bias   = (const float*)d_in[2];
    const float* Aq     = (const float*)d_in[3];
    const float* Bq     = (const float*)d_in[4];
    const float* Av     = (const float*)d_in[5];
    const float* Bv     = (const float*)d_in[6];
    const int*   idx    = (const int*)d_in[7];
    float* out = (float*)d_out;

    // workspace: Xc(64MB) | Wk(2MB) | Wmq(16MB) | Wmv(16MB) = 98MB
    u16* Xc  = (u16*)d_ws;
    u16* Wk  = Xc + (size_t)MROWS * DIM;
    u16* Wmq = Wk + (size_t)DIM * DIM;
    u16* Wmv = Wmq + (size_t)8 * DIM * DIM;

    hipFuncSetAttribute(reinterpret_cast<const void*>(k_gemm),
                        hipFuncAttributeMaxDynamicSharedMemorySize, 98304);

    k_convert<<<2048, 256, 0, stream>>>(x, Xc, MROWS * DIM);
    k_convert<<<512, 256, 0, stream>>>(weight + (size_t)DIM * DIM, Wk, DIM * DIM);
    k_build<<<1024, 256, 0, stream>>>(weight, Aq, Bq, Av, Bv, idx, Wmq, Wmv);
    k_gemm<<<1536, 1024, 98304, stream>>>(Xc, Wk, Wmq, Wmv, bias, idx, out);
}

// Round 7
// 321.695 us; speedup vs baseline: 1.2418x; 1.0100x over previous
//
#include <hip/hip_runtime.h>
#include <hip/hip_bf16.h>
#include <stdint.h>

#define DIM   1024
#define ODIM  3072
#define MROWS 32768   // B(8) * N(4096)
#define RANK  8
#define BK    32

typedef unsigned short u16;
typedef __attribute__((ext_vector_type(8))) short short8;
typedef __attribute__((ext_vector_type(8))) unsigned short u16x8;
typedef __attribute__((ext_vector_type(4))) unsigned short u16x4;
typedef __attribute__((ext_vector_type(4))) float f32x4;

__device__ __forceinline__ u16 f2bf(float f) {
    uint32_t u = __float_as_uint(f);
    u += 0x7fffu + ((u >> 16) & 1u);   // RNE
    return (u16)(u >> 16);
}

__device__ __forceinline__ void gl2lds16(const void* g, void* l) {
    __builtin_amdgcn_global_load_lds(
        (const __attribute__((address_space(1))) void*)(uintptr_t)g,
        (__attribute__((address_space(3))) void*)(uint32_t)(uintptr_t)l,
        16, 0, 0);
}

#define BAR()    do { asm volatile("" ::: "memory"); __builtin_amdgcn_s_barrier(); asm volatile("" ::: "memory"); } while (0)
#define WAITV2() asm volatile("s_waitcnt vmcnt(2)" ::: "memory")
#define WAITV0() asm volatile("s_waitcnt vmcnt(0)" ::: "memory")

// ---------------- f32 -> bf16 conversion ----------------
__global__ __launch_bounds__(256) void k_convert(const float* __restrict__ src,
                                                 u16* __restrict__ dst, int n) {
    const int stride = gridDim.x * blockDim.x;
    for (int t = blockIdx.x * blockDim.x + threadIdx.x; t * 8 < n; t += stride) {
        const int i = t * 8;
        float4 a = *reinterpret_cast<const float4*>(src + i);
        float4 b = *reinterpret_cast<const float4*>(src + i + 4);
        u16x8 o;
        o[0] = f2bf(a.x); o[1] = f2bf(a.y); o[2] = f2bf(a.z); o[3] = f2bf(a.w);
        o[4] = f2bf(b.x); o[5] = f2bf(b.y); o[6] = f2bf(b.z); o[7] = f2bf(b.w);
        *reinterpret_cast<u16x8*>(dst + i) = o;
    }
}

// ---------------- Wmod[b] = W_slab + (A[idx_b] @ B[idx_b])^T, bf16 ----------------
__global__ __launch_bounds__(256) void k_build(const float* __restrict__ W,
                                               const float* __restrict__ Aq_pool,
                                               const float* __restrict__ Bq_pool,
                                               const float* __restrict__ Av_pool,
                                               const float* __restrict__ Bv_pool,
                                               const int* __restrict__ idx,
                                               u16* __restrict__ Wmq,
                                               u16* __restrict__ Wmv) {
    const int b  = blockIdx.x >> 7;
    const int s  = (blockIdx.x >> 6) & 1;
    const int og = blockIdx.x & 63;
    const int p  = idx[b];
    const float* A  = (s ? Av_pool : Aq_pool) + (size_t)p * DIM * RANK;
    const float* Bp = (s ? Bv_pool : Bq_pool) + (size_t)p * RANK * DIM;
    const float* Ws = W + (size_t)(s ? 2048 : 0) * DIM;
    u16* dst = (s ? Wmv : Wmq) + (size_t)b * DIM * DIM;

    const int t  = threadIdx.x;
    const int i0 = t * 4;
    float a[4][8];
    #pragma unroll
    for (int ii = 0; ii < 4; ++ii) {
        float4 a0 = reinterpret_cast<const float4*>(A + (size_t)(i0 + ii) * RANK)[0];
        float4 a1 = reinterpret_cast<const float4*>(A + (size_t)(i0 + ii) * RANK)[1];
        a[ii][0] = a0.x; a[ii][1] = a0.y; a[ii][2] = a0.z; a[ii][3] = a0.w;
        a[ii][4] = a1.x; a[ii][5] = a1.y; a[ii][6] = a1.z; a[ii][7] = a1.w;
    }
    for (int r = 0; r < 16; ++r) {
        const int o = og * 16 + r;
        float bv[8];
        #pragma unroll
        for (int rr = 0; rr < 8; ++rr) bv[rr] = Bp[(size_t)rr * DIM + o];
        float4 w = *reinterpret_cast<const float4*>(Ws + (size_t)o * DIM + i0);
        float v[4] = {w.x, w.y, w.z, w.w};
        u16x4 ov;
        #pragma unroll
        for (int ii = 0; ii < 4; ++ii) {
            float d = 0.f;
            #pragma unroll
            for (int rr = 0; rr < 8; ++rr) d += a[ii][rr] * bv[rr];
            ov[ii] = f2bf(v[ii] + d);
        }
        *reinterpret_cast<u16x4*>(dst + (size_t)o * DIM + i0) = ov;
    }
}

// ---------------- 256x256 16-wave triple-buffered GEMM, BK=32 ----------------
// 16 waves (4Mx4N), per-wave 64x64; 3 buffers x (A 256x32 + B 256x32) = 96 KiB.
// LDS layout (128B rows, conflict-free — R4-family):
//   matrix row r, k-group gk (8 u16) -> LDS row R=r>>1 (64 u16 = 128B),
//   slot p = ((r&1)*4 + gk) ^ (R&7).  Bank index depends only on p -> any
//   8-lane beat covers all 32 banks once (verified for consecutive-8,
//   16-lane, and {l,l+16,l+32,l+48} groupings).
// Write side: gl2lds16 linear dest (lane l -> row l>>3, slot l&7); global
// source pre-permuted by the inverse: q=(l&7)^(l>>3), r_local=(l>>3)*2+(q>>2),
// gk=q&3  (both-sides involution, rule #21).
// Schedule per tile t: stage(t+2) -> 8 ds_read -> 16 MFMA(setprio) ->
// vmcnt(2) -> ONE barrier. Triple buffer => race-free with single barrier.

__device__ __forceinline__ void stage(const u16* __restrict__ Xc,
                                      const u16* __restrict__ Bm,
                                      int m0, int nc, int tk,
                                      u16* buf, int wave, int lane) {
    const int q  = (lane & 7) ^ (lane >> 3);
    const int rl = (lane >> 3) * 2 + (q >> 2);      // matrix row within wave's 16
    const int gk = q & 3;                            // k-group
    const u16* ga = Xc + (size_t)(m0 + wave * 16 + rl) * DIM + tk + gk * 8;
    const u16* gb = Bm + (size_t)(nc + wave * 16 + rl) * DIM + tk + gk * 8;
    gl2lds16(ga, buf + wave * 512);
    gl2lds16(gb, buf + 8192 + wave * 512);
}

__device__ __forceinline__ void tile_mfma(const u16* __restrict__ buf,
                                          int wr, int wc, int axc,
                                          f32x4 (&acc)[4][4]) {
    short8 a[4], b[4];
    #pragma unroll
    for (int f = 0; f < 4; ++f)
        a[f] = *reinterpret_cast<const short8*>(buf + wr * 2048 + f * 512 + axc);
    #pragma unroll
    for (int n = 0; n < 4; ++n)
        b[n] = *reinterpret_cast<const short8*>(buf + 8192 + wc * 2048 + n * 512 + axc);
    __builtin_amdgcn_s_setprio(1);
    #pragma unroll
    for (int f = 0; f < 4; ++f)
        #pragma unroll
        for (int n = 0; n < 4; ++n)
            acc[f][n] = __builtin_amdgcn_mfma_f32_16x16x32_bf16(a[f], b[n], acc[f][n], 0, 0, 0);
    __builtin_amdgcn_s_setprio(0);
}

__global__ __launch_bounds__(1024, 4) void k_gemm(const u16* __restrict__ Xc,
                                                  const u16* __restrict__ Wk,
                                                  const u16* __restrict__ Wmq,
                                                  const u16* __restrict__ Wmv,
                                                  const float* __restrict__ bias,
                                                  float* __restrict__ out) {
    extern __shared__ u16 lds[];               // 96 KiB: 3 x 16384 u16
    const int tid  = threadIdx.x;
    const int lane = tid & 63, wave = tid >> 6;
    const int wr = wave >> 2, wc = wave & 3;   // 4M x 4N wave grid, 64x64 each

    // bijective XCD swizzle (nwg=1536, 1536%8==0)
    const int orig = blockIdx.x;
    const int wg   = (orig & 7) * 192 + (orig >> 3);
    const int bn   = wg % 12;
    const int bm   = wg / 12;
    const int m0 = bm * 256, n0 = bn * 256;
    const int batch = m0 >> 12;

    const u16* Bmat;
    int nc;
    if (n0 < DIM)           { Bmat = Wmq + (size_t)batch * DIM * DIM; nc = n0; }
    else if (n0 < 2 * DIM)  { Bmat = Wk;                              nc = n0 - DIM; }
    else                    { Bmat = Wmv + (size_t)batch * DIM * DIM; nc = n0 - 2 * DIM; }

    // per-lane read offset: matrix row lr=lane&15 within frag, k-group lane>>4
    const int lr  = lane & 15;
    const int axc = (lr >> 1) * 64 + ((((lr & 1) * 4) + (lane >> 4)) ^ (lr >> 1)) * 8;

    u16* b0 = lds;
    u16* b1 = lds + 16384;
    u16* b2 = lds + 32768;

    f32x4 acc[4][4] = {};

    // prologue: stage tiles 0,1
    stage(Xc, Bmat, m0, nc, 0,  b0, wave, lane);
    stage(Xc, Bmat, m0, nc, BK, b1, wave, lane);
    WAITV2(); BAR();                           // tile 0 landed (all waves)

    #pragma unroll 1
    for (int t3 = 0; t3 < 30; t3 += 3) {
        stage(Xc, Bmat, m0, nc, (t3 + 2) * BK, b2, wave, lane);
        tile_mfma(b0, wr, wc, axc, acc);
        WAITV2(); BAR();

        stage(Xc, Bmat, m0, nc, (t3 + 3) * BK, b0, wave, lane);
        tile_mfma(b1, wr, wc, axc, acc);
        WAITV2(); BAR();

        stage(Xc, Bmat, m0, nc, (t3 + 4) * BK, b1, wave, lane);
        tile_mfma(b2, wr, wc, axc, acc);
        WAITV2(); BAR();
    }
    // t = 30: read b0, no stage; drain tile 31's loads
    tile_mfma(b0, wr, wc, axc, acc);
    WAITV0(); BAR();
    // t = 31: read b1
    tile_mfma(b1, wr, wc, axc, acc);

    // ---------------- epilogue: bias + store ----------------
    const int cn = wc * 64 + (lane & 15);
    float bcol[4];
    #pragma unroll
    for (int n = 0; n < 4; ++n) bcol[n] = bias[n0 + cn + n * 16];
    #pragma unroll
    for (int f = 0; f < 4; ++f) {
        const int rb = m0 + wr * 64 + f * 16 + (lane >> 4) * 4;
        #pragma unroll
        for (int v = 0; v < 4; ++v) {
            const size_t row = (size_t)(rb + v);
            #pragma unroll
            for (int n = 0; n < 4; ++n)
                out[row * ODIM + (size_t)(n0 + cn + n * 16)] = acc[f][n][v] + bcol[n];
        }
    }
}

extern "C" void kernel_launch(void* const* d_in, const int* in_sizes, int n_in,
                              void* d_out, int out_size, void* d_ws, size_t ws_size,
                              hipStream_t stream) {
    const float* x      = (const float*)d_in[0];
    const float* weight = (const float*)d_in[1];
    const float* bias   = (const float*)d_in[2];
    const float* Aq     = (const float*)d_in[3];
    const float* Bq     = (const float*)d_in[4];
    const float* Av     = (const float*)d_in[5];
    const float* Bv     = (const float*)d_in[6];
    const int*   idx    = (const int*)d_in[7];
    float* out = (float*)d_out;

    // workspace: Xc(64MB) | Wk(2MB) | Wmq(16MB) | Wmv(16MB) = 98MB
    u16* Xc  = (u16*)d_ws;
    u16* Wk  = Xc + (size_t)MROWS * DIM;
    u16* Wmq = Wk + (size_t)DIM * DIM;
    u16* Wmv = Wmq + (size_t)8 * DIM * DIM;

    hipFuncSetAttribute(reinterpret_cast<const void*>(k_gemm),
                        hipFuncAttributeMaxDynamicSharedMemorySize, 98304);

    k_convert<<<2048, 256, 0, stream>>>(x, Xc, MROWS * DIM);
    k_convert<<<512, 256, 0, stream>>>(weight + (size_t)DIM * DIM, Wk, DIM * DIM);
    k_build<<<1024, 256, 0, stream>>>(weight, Aq, Bq, Av, Bv, idx, Wmq, Wmv);
    k_gemm<<<1536, 1024, 98304, stream>>>(Xc, Wk, Wmq, Wmv, bias, out);
}

// Round 9
// 298.173 us; speedup vs baseline: 1.3397x; 1.0789x over previous
//
#include <hip/hip_runtime.h>
#include <hip/hip_bf16.h>
#include <stdint.h>

#define DIM   1024
#define ODIM  3072
#define MROWS 32768   // B(8) * N(4096)
#define RANK  8

typedef unsigned short u16;
typedef __attribute__((ext_vector_type(8))) short short8;
typedef __attribute__((ext_vector_type(8))) unsigned short u16x8;
typedef __attribute__((ext_vector_type(4))) unsigned short u16x4;
typedef __attribute__((ext_vector_type(4))) float f32x4;

__device__ __forceinline__ u16 f2bf(float f) {
    uint32_t u = __float_as_uint(f);
    u += 0x7fffu + ((u >> 16) & 1u);   // RNE
    return (u16)(u >> 16);
}

__device__ __forceinline__ void gl2lds16(const void* g, void* l) {
    __builtin_amdgcn_global_load_lds(
        (const __attribute__((address_space(1))) void*)(uintptr_t)g,
        (__attribute__((address_space(3))) void*)(uint32_t)(uintptr_t)l,
        16, 0, 0);
}

#define BAR()    do { asm volatile("" ::: "memory"); __builtin_amdgcn_s_barrier(); asm volatile("" ::: "memory"); } while (0)
#define WAITV4() asm volatile("s_waitcnt vmcnt(4)" ::: "memory")
#define WAITV2() asm volatile("s_waitcnt vmcnt(2)" ::: "memory")
#define WAITV0() asm volatile("s_waitcnt vmcnt(0)" ::: "memory")
#define WAITL0() asm volatile("s_waitcnt lgkmcnt(0)" ::: "memory")
#define WAITL8() asm volatile("s_waitcnt lgkmcnt(8)" ::: "memory")
#define SCHED0() __builtin_amdgcn_sched_barrier(0)

// ---------------- f32 -> bf16 conversion ----------------
__global__ __launch_bounds__(256) void k_convert(const float* __restrict__ src,
                                                 u16* __restrict__ dst, int n) {
    const int stride = gridDim.x * blockDim.x;
    for (int t = blockIdx.x * blockDim.x + threadIdx.x; t * 8 < n; t += stride) {
        const int i = t * 8;
        float4 a = *reinterpret_cast<const float4*>(src + i);
        float4 b = *reinterpret_cast<const float4*>(src + i + 4);
        u16x8 o;
        o[0] = f2bf(a.x); o[1] = f2bf(a.y); o[2] = f2bf(a.z); o[3] = f2bf(a.w);
        o[4] = f2bf(b.x); o[5] = f2bf(b.y); o[6] = f2bf(b.z); o[7] = f2bf(b.w);
        *reinterpret_cast<u16x8*>(dst + i) = o;
    }
}

// ---------------- Wmod[b] = W_slab + (A[idx_b] @ B[idx_b])^T, bf16 ----------------
__global__ __launch_bounds__(256) void k_build(const float* __restrict__ W,
                                               const float* __restrict__ Aq_pool,
                                               const float* __restrict__ Bq_pool,
                                               const float* __restrict__ Av_pool,
                                               const float* __restrict__ Bv_pool,
                                               const int* __restrict__ idx,
                                               u16* __restrict__ Wmq,
                                               u16* __restrict__ Wmv) {
    const int b  = blockIdx.x >> 7;
    const int s  = (blockIdx.x >> 6) & 1;
    const int og = blockIdx.x & 63;
    const int p  = idx[b];
    const float* A  = (s ? Av_pool : Aq_pool) + (size_t)p * DIM * RANK;
    const float* Bp = (s ? Bv_pool : Bq_pool) + (size_t)p * RANK * DIM;
    const float* Ws = W + (size_t)(s ? 2048 : 0) * DIM;
    u16* dst = (s ? Wmv : Wmq) + (size_t)b * DIM * DIM;

    const int t  = threadIdx.x;
    const int i0 = t * 4;
    float a[4][8];
    #pragma unroll
    for (int ii = 0; ii < 4; ++ii) {
        float4 a0 = reinterpret_cast<const float4*>(A + (size_t)(i0 + ii) * RANK)[0];
        float4 a1 = reinterpret_cast<const float4*>(A + (size_t)(i0 + ii) * RANK)[1];
        a[ii][0] = a0.x; a[ii][1] = a0.y; a[ii][2] = a0.z; a[ii][3] = a0.w;
        a[ii][4] = a1.x; a[ii][5] = a1.y; a[ii][6] = a1.z; a[ii][7] = a1.w;
    }
    for (int r = 0; r < 16; ++r) {
        const int o = og * 16 + r;
        float bv[8];
        #pragma unroll
        for (int rr = 0; rr < 8; ++rr) bv[rr] = Bp[(size_t)rr * DIM + o];
        float4 w = *reinterpret_cast<const float4*>(Ws + (size_t)o * DIM + i0);
        float v[4] = {w.x, w.y, w.z, w.w};
        u16x4 ov;
        #pragma unroll
        for (int ii = 0; ii < 4; ++ii) {
            float d = 0.f;
            #pragma unroll
            for (int rr = 0; rr < 8; ++rr) d += a[ii][rr] * bv[rr];
            ov[ii] = f2bf(v[ii] + d);
        }
        *reinterpret_cast<u16x4*>(dst + (size_t)o * DIM + i0) = ov;
    }
}

// ---------------- 256x256 8-wave 8-phase GEMM (count-guaranteed waits) -----------
// BK=64; LDS 2 buffers x (A 256x64 + B 256x64) = 128 KiB; 128B rows,
// swizzle: 16B group g of row r at slot g^(r&7) (0-conflict, R4/R7-proven),
// staged via pre-swizzled global source (rule #21).
// Fragment map (progressive halves): A m-frag f: rows wr*64+(f&3)*16+(f>>2)*128
// (f<4 -> A-half0); B n-frag n: rows wc*16+n*64 (n<2 -> B-half0).
// Stage order per tile: A0@ph0, B0@ph1, B1@ph2, A1@ph3 (of tile t+1).
// vmcnt ledger (2 loads/half; invariant {B1(t),A1(t)}=4 at tile start):
//   end ph0: vmcnt(4) retires B1(t)        (read at ph1)
//   end ph1: vmcnt(4) retires A1(t)        (read at ph2)
//   end ph2: no wait                        (ph3 reads nothing)
//   end ph3: vmcnt(4) retires A0,B0(t+1)   (both read at ph0 of t+1)
// EVERY read is count-retired + barrier-covered — no latency assumptions.
// Tail (tile 15, no staging): drain 4 -> 2 (ph0) -> 0 (ph1).

__device__ __forceinline__ void stage_half(const u16* __restrict__ mat, int row0, int tk,
                                           u16* dst, int wave, int lane) {
    const int lrow = lane >> 3;
    const int g    = (lane & 7) ^ lrow;          // pre-swizzled 16B group
    const u16* gp = mat + (size_t)(row0 + wave * 8 + lrow) * DIM + tk + g * 8;
    u16* lp = dst + wave * 8 * 64;               // wave-uniform LDS base
    gl2lds16(gp, lp);
    gl2lds16(gp + (size_t)64 * DIM, lp + 64 * 64);
}

__device__ __forceinline__ void ds_read_A(const u16* sA, int wr, int lane,
                                          int kx0, int kx1, int mh, short8 (&a)[4][2]) {
    #pragma unroll
    for (int f = 0; f < 4; ++f) {
        const int row = wr * 64 + f * 16 + mh * 128 + (lane & 15);
        a[f][0] = *reinterpret_cast<const short8*>(sA + row * 64 + kx0);
        a[f][1] = *reinterpret_cast<const short8*>(sA + row * 64 + kx1);
    }
}
__device__ __forceinline__ void ds_read_B(const u16* sB, int wc, int lane,
                                          int kx0, int kx1, int nh, short8 (&b)[2][2]) {
    #pragma unroll
    for (int f = 0; f < 2; ++f) {
        const int row = wc * 16 + (nh * 2 + f) * 64 + (lane & 15);
        b[f][0] = *reinterpret_cast<const short8*>(sB + row * 64 + kx0);
        b[f][1] = *reinterpret_cast<const short8*>(sB + row * 64 + kx1);
    }
}

template <int MH, int NH>
__device__ __forceinline__ void mfma_quad(const short8 (&a)[4][2], const short8 (&b)[2][2],
                                          f32x4 (&acc)[8][4]) {
    #pragma unroll
    for (int ks = 0; ks < 2; ++ks)
        #pragma unroll
        for (int f = 0; f < 4; ++f)
            #pragma unroll
            for (int g = 0; g < 2; ++g)
                acc[MH * 4 + f][NH * 2 + g] = __builtin_amdgcn_mfma_f32_16x16x32_bf16(
                    a[f][ks], b[g][ks], acc[MH * 4 + f][NH * 2 + g], 0, 0, 0);
}

#define MFMA_BLOCK(MH, NH, AREG, BREG)                  \
    do {                                                \
        BAR();                                          \
        WAITL0();                                       \
        SCHED0();                                       \
        __builtin_amdgcn_s_setprio(1);                  \
        mfma_quad<MH, NH>(AREG, BREG, acc);             \
        __builtin_amdgcn_s_setprio(0);                  \
        SCHED0();                                       \
    } while (0)

__global__ __launch_bounds__(512, 2) void k_gemm(const u16* __restrict__ Xc,
                                                 const u16* __restrict__ Wk,
                                                 const u16* __restrict__ Wmq,
                                                 const u16* __restrict__ Wmv,
                                                 const float* __restrict__ bias,
                                                 float* __restrict__ out) {
    extern __shared__ u16 lds[];               // 128 KiB
    const int tid  = threadIdx.x;
    const int lane = tid & 63, wave = tid >> 6;
    const int wr = wave >> 2, wc = wave & 3;   // 2M x 4N wave grid

    // bijective XCD swizzle (nwg=1536, 1536%8==0)
    const int orig = blockIdx.x;
    const int wg   = (orig & 7) * 192 + (orig >> 3);
    const int bn   = wg % 12;
    const int bm   = wg / 12;
    const int m0 = bm * 256, n0 = bn * 256;
    const int batch = m0 >> 12;

    const u16* Bmat;
    int nc;
    if (n0 < DIM)           { Bmat = Wmq + (size_t)batch * DIM * DIM; nc = n0; }
    else if (n0 < 2 * DIM)  { Bmat = Wk;                              nc = n0 - DIM; }
    else                    { Bmat = Wmv + (size_t)batch * DIM * DIM; nc = n0 - 2 * DIM; }

    const int kx0 = (((lane >> 4)    ) ^ (lane & 7)) * 8;
    const int kx1 = (((lane >> 4) + 4) ^ (lane & 7)) * 8;

    f32x4 acc[8][4] = {};

    // prologue: tile 0 fully into buffer 0, drain once
    stage_half(Xc,   m0,       0, lds,                    wave, lane);
    stage_half(Bmat, nc,       0, lds + 16384,            wave, lane);
    stage_half(Bmat, nc + 128, 0, lds + 16384 + 128 * 64, wave, lane);
    stage_half(Xc,   m0 + 128, 0, lds + 128 * 64,         wave, lane);
    WAITV0(); BAR();

    #pragma unroll 1
    for (int t = 0; t < 15; ++t) {
        const u16* sA = lds + (t & 1) * 32768;
        const u16* sB = sA + 16384;
        u16* wA = lds + ((t + 1) & 1) * 32768;
        u16* wB = wA + 16384;
        const int tk1 = (t + 1) * 64;
        short8 a_lo[4][2], a_hi[4][2], b0[2][2], b1[2][2];

        // ---- phase 0: read Ah0(8)+Bh0(4); stage A0(t+1); quad(0,0) ----
        ds_read_A(sA, wr, lane, kx0, kx1, 0, a_lo);
        ds_read_B(sB, wc, lane, kx0, kx1, 0, b0);
        stage_half(Xc, m0, tk1, wA, wave, lane);
        WAITL8();
        MFMA_BLOCK(0, 0, a_lo, b0);
        WAITV4(); BAR();               // retire B1(t) (read next phase)

        // ---- phase 1: read Bh1(4); stage B0(t+1); quad(0,1) ----
        ds_read_B(sB, wc, lane, kx0, kx1, 1, b1);
        stage_half(Bmat, nc, tk1, wB, wave, lane);
        MFMA_BLOCK(0, 1, a_lo, b1);
        WAITV4(); BAR();               // retire A1(t) (read next phase)

        // ---- phase 2: read Ah1(8); stage B1(t+1); quad(1,0) ----
        ds_read_A(sA, wr, lane, kx0, kx1, 1, a_hi);
        stage_half(Bmat, nc + 128, tk1, wB + 128 * 64, wave, lane);
        MFMA_BLOCK(1, 0, a_hi, b0);
        BAR();

        // ---- phase 3: no reads; stage A1(t+1); quad(1,1); boundary ----
        stage_half(Xc, m0 + 128, tk1, wA + 128 * 64, wave, lane);
        MFMA_BLOCK(1, 1, a_hi, b1);
        WAITV4(); BAR();               // retire A0(t+1), B0(t+1) (read at ph0)
    }

    // ---- peeled tail: tile 15, no staging; count-guaranteed drain ----
    {
        const u16* sA = lds + 32768;   // 15 & 1 == 1
        const u16* sB = sA + 16384;
        short8 a_lo[4][2], a_hi[4][2], b0[2][2], b1[2][2];

        ds_read_A(sA, wr, lane, kx0, kx1, 0, a_lo);
        ds_read_B(sB, wc, lane, kx0, kx1, 0, b0);
        WAITL8();
        MFMA_BLOCK(0, 0, a_lo, b0);
        WAITV2(); BAR();               // retire B1(15) before its read

        ds_read_B(sB, wc, lane, kx0, kx1, 1, b1);
        MFMA_BLOCK(0, 1, a_lo, b1);
        WAITV0(); BAR();               // retire A1(15) before its read

        ds_read_A(sA, wr, lane, kx0, kx1, 1, a_hi);
        MFMA_BLOCK(1, 0, a_hi, b0);
        BAR();

        MFMA_BLOCK(1, 1, a_hi, b1);
    }

    // ---------------- epilogue: bias + store ----------------
    const int cn = wc * 16 + (lane & 15);      // col within 256-block, + ni*64
    float bcol[4];
    #pragma unroll
    for (int ni = 0; ni < 4; ++ni) bcol[ni] = bias[n0 + cn + ni * 64];
    #pragma unroll
    for (int mi = 0; mi < 8; ++mi) {
        const int rb = m0 + wr * 64 + (mi & 3) * 16 + (mi >> 2) * 128 + (lane >> 4) * 4;
        #pragma unroll
        for (int v = 0; v < 4; ++v) {
            const size_t row = (size_t)(rb + v);
            #pragma unroll
            for (int ni = 0; ni < 4; ++ni)
                out[row * ODIM + (size_t)(n0 + cn + ni * 64)] = acc[mi][ni][v] + bcol[ni];
        }
    }
}

extern "C" void kernel_launch(void* const* d_in, const int* in_sizes, int n_in,
                              void* d_out, int out_size, void* d_ws, size_t ws_size,
                              hipStream_t stream) {
    const float* x      = (const float*)d_in[0];
    const float* weight = (const float*)d_in[1];
    const float* bias   = (const float*)d_in[2];
    const float* Aq     = (const float*)d_in[3];
    const float* Bq     = (const float*)d_in[4];
    const float* Av     = (const float*)d_in[5];
    const float* Bv     = (const float*)d_in[6];
    const int*   idx    = (const int*)d_in[7];
    float* out = (float*)d_out;

    // workspace: Xc(64MB) | Wk(2MB) | Wmq(16MB) | Wmv(16MB) = 98MB
    u16* Xc  = (u16*)d_ws;
    u16* Wk  = Xc + (size_t)MROWS * DIM;
    u16* Wmq = Wk + (size_t)DIM * DIM;
    u16* Wmv = Wmq + (size_t)8 * DIM * DIM;

    hipFuncSetAttribute(reinterpret_cast<const void*>(k_gemm),
                        hipFuncAttributeMaxDynamicSharedMemorySize, 131072);

    k_convert<<<2048, 256, 0, stream>>>(x, Xc, MROWS * DIM);
    k_convert<<<512, 256, 0, stream>>>(weight + (size_t)DIM * DIM, Wk, DIM * DIM);
    k_build<<<1024, 256, 0, stream>>>(weight, Aq, Bq, Av, Bv, idx, Wmq, Wmv);
    k_gemm<<<1536, 512, 131072, stream>>>(Xc, Wk, Wmq, Wmv, bias, out);
}